// Round 3
// baseline (89.866 us; speedup 1.0000x reference)
//
#include <hip/hip_runtime.h>

#define L_SEQ   512
#define NHEADS_ 8
#define HEADDIM_ 128
#define QKD     16
#define DINNER  1024
#define EPS_F   1e-3f
#define STD_F   0.0078125f   // 1/sqrt(2*512*16) = 1/128

// LDS layout for KS[t_local][l]: addr = t*KS_ROW + (l>>5)*33 + (l&31)
// KS_ROW=529 (529%32=17); phase-A stores and phase-B reads both <=2-way (free).
#define KS_ROW  529

typedef __attribute__((ext_vector_type(8))) short  short8;
typedef __attribute__((ext_vector_type(4))) float  floatx4;
typedef __attribute__((ext_vector_type(2))) float  float2v;

// cos(2*pi*rev): v_cos_f32 takes revolutions; reduce to [0,1) first.
__device__ __forceinline__ float cosrev(float rev) {
    float r = rev - floorf(rev);
    return __builtin_amdgcn_cosf(r);
}

// 2*cos(2*pi*a) for tiny |a| (<= ~0.008 rev): even poly, err ~2e-12.
__device__ __forceinline__ float two_cos_small(float a) {
    float x = a * a;
    return fmaf(fmaf(x, 129.8787876f, -39.4784176f), x, 2.0f);
}

// 8 floats -> short8 of bf16 via v_cvt_pk_bf16_f32 (RNE, 2 floats/inst).
// dst.lo16 = bf16(src0), dst.hi16 = bf16(src1) -> elements (2p, 2p+1).
__device__ __forceinline__ short8 pack_bf16x8(const float* s) {
    union { int i[4]; short8 v; } u;
#pragma unroll
    for (int p = 0; p < 4; ++p)
        asm("v_cvt_pk_bf16_f32 %0, %1, %2"
            : "=v"(u.i[p]) : "v"(s[2 * p]), "v"(s[2 * p + 1]));
    return u.v;
}

// Single fused kernel — NO workspace use (theory: the harness's 256 MiB
// workspace re-poison fill (~42 us, seen in rocprof) sits in the timed window;
// dropping d_ws entirely removes that tax plus the vtrans launch).
// B-operand now read straight from f32 v: for a fixed k-slot the 16 lanes tl
// read 16 consecutive floats (one 64B line, 100% used), converted on the fly
// with v_cvt_pk_bf16_f32 (4 inst / 8 elems, RNE).
// Block = 4 waves, 16 t-rows, one (b,n); waves split l 4-ways (128 each).
__global__ __launch_bounds__(256, 3) void vand_fused(const float* __restrict__ v,
                                                     const float* __restrict__ q,
                                                     const float* __restrict__ k,
                                                     float* __restrict__ out) {
    const int tid  = threadIdx.x;
    const int w    = tid >> 6;
    const int lane = tid & 63;
    const int tl   = lane & 15;
    const int quad = lane >> 4;
    const int ttile = blockIdx.x;     // 0..31
    const int bn    = blockIdx.y;     // 0..15
    const int b = bn >> 3, n = bn & 7;
    const float t0f = (float)(ttile * 16);

    __shared__ float smem[16 * KS_ROW];         // 33.9 KB: ksl (phases A/B), red (epilogue)
    float* ksl = smem;

    // ---- Phase A: KS[t][l] for t in tile, l in THIS WAVE's 128-range ----
    // Wave w writes l in [w*128, w*128+128) and reads back only that range in
    // phase B -> same-wave ds ordering suffices, NO __syncthreads needed.
#pragma unroll
    for (int rep = 0; rep < 2; ++rep) {
        const int l = w * 128 + rep * 64 + lane;
        const float* krow = k + ((size_t)(b * L_SEQ + l)) * (NHEADS_ * QKD) + n * QKD;
        float kk[16];
#pragma unroll
        for (int d4 = 0; d4 < 4; ++d4) {
            float4 t4 = *(const float4*)(krow + 4 * d4);
            kk[d4 * 4 + 0] = t4.x; kk[d4 * 4 + 1] = t4.y;
            kk[d4 * 4 + 2] = t4.z; kk[d4 * 4 + 3] = t4.w;
        }
        float2v M2[8], C1[8], C0[8];
#pragma unroll
        for (int i = 0; i < 8; ++i) {
            float a0 = EPS_F * kk[2 * i], a1 = EPS_F * kk[2 * i + 1];
            M2[i].x = two_cos_small(a0);         M2[i].y = two_cos_small(a1);
            C1[i].x = cosrev(a0 * t0f);          C1[i].y = cosrev(a1 * t0f);
            C0[i].x = cosrev(a0 * (t0f - 1.f));  C0[i].y = cosrev(a1 * (t0f - 1.f));
        }
        const int base = (l >> 5) * 33 + (l & 31);
#pragma unroll
        for (int m = 0; m < 16; ++m) {
            float2v s = ((C1[0] + C1[1]) + (C1[2] + C1[3]))
                      + ((C1[4] + C1[5]) + (C1[6] + C1[7]));
            ksl[m * KS_ROW + base] = s.x + s.y;
#pragma unroll
            for (int i = 0; i < 8; ++i) {
                float2v nx = M2[i] * C1[i] - C0[i];
                C0[i] = C1[i];
                C1[i] = nx;
            }
        }
    }

    // ---- Phase B: q-part recurrence + subtract KS + MFMA ----
    const int   t   = ttile * 16 + tl;
    const int   l0  = w * 128 + quad * 32;
    const float l0f = (float)l0;

    const float* qrow = q + ((size_t)(b * L_SEQ + t)) * (NHEADS_ * QKD) + n * QKD;
    float2v M2[8], C1[8], C0[8];
#pragma unroll
    for (int d4 = 0; d4 < 4; ++d4) {
        float4 qq = *(const float4*)(qrow + 4 * d4);
        float aa[4] = {EPS_F * qq.x, EPS_F * qq.y, EPS_F * qq.z, EPS_F * qq.w};
#pragma unroll
        for (int e = 0; e < 2; ++e) {
            int i = d4 * 2 + e;
            float a0 = aa[2 * e], a1 = aa[2 * e + 1];
            M2[i].x = two_cos_small(a0);         M2[i].y = two_cos_small(a1);
            C1[i].x = cosrev(a0 * l0f);          C1[i].y = cosrev(a1 * l0f);
            C0[i].x = cosrev(a0 * (l0f - 1.f));  C0[i].y = cosrev(a1 * (l0f - 1.f));
        }
    }

    // v slice for this (b,n): v[b, l, n*128 + h], row stride DINNER floats
    const float* vslice = v + ((size_t)b * L_SEQ) * DINNER + n * HEADDIM_;
    const int klds = tl * KS_ROW + (4 * w + quad) * 33;

    floatx4 acc[8] = {};

#pragma unroll
    for (int c = 0; c < 4; ++c) {
        float kv[8];
#pragma unroll
        for (int jj = 0; jj < 8; ++jj) kv[jj] = ksl[klds + c * 8 + jj];
        float ss[8];
#pragma unroll
        for (int jj = 0; jj < 8; ++jj) {
            float2v sv = ((C1[0] + C1[1]) + (C1[2] + C1[3]))
                       + ((C1[4] + C1[5]) + (C1[6] + C1[7]));
            ss[jj] = (sv.x + sv.y) - kv[jj];
#pragma unroll
            for (int i = 0; i < 8; ++i) {
                float2v nx = M2[i] * C1[i] - C0[i];
                C0[i] = C1[i];
                C1[i] = nx;
            }
        }
        const short8 af = pack_bf16x8(ss);

        // B-operand: lane (tl,quad) needs v[l = w*128+quad*32+c*8+jj][h = ht*16+tl]
        const float* vcp = vslice + (size_t)(w * 128 + quad * 32 + c * 8) * DINNER + tl;
#pragma unroll
        for (int ht = 0; ht < 8; ++ht) {
            float fv[8];
#pragma unroll
            for (int jj = 0; jj < 8; ++jj)
                fv[jj] = vcp[(size_t)jj * DINNER + ht * 16];
            const short8 bfr = pack_bf16x8(fv);
            acc[ht] = __builtin_amdgcn_mfma_f32_16x16x32_bf16(af, bfr, acc[ht], 0, 0, 0);
        }
    }

    // ---- split-K reduction + epilogue (red overlays ksl; barrier both sides) ----
    __syncthreads();   // all waves done reading ksl before it is clobbered
    float (*red)[64][33] = (float (*)[64][33])smem;   // 4*64*33 = 8448 <= 16*529
#pragma unroll
    for (int ht = 0; ht < 8; ++ht)
#pragma unroll
        for (int r = 0; r < 4; ++r)
            red[w][lane][ht * 4 + r] = acc[ht][r];
    __syncthreads();

    float* obase = out + ((size_t)b * L_SEQ) * DINNER + n * HEADDIM_;
#pragma unroll
    for (int i = 0; i < 2; ++i) {
        int g    = i * 256 + tid;      // 512 float4 groups (16 t x 32 h-quads)
        int hb   = g & 31;             // h = hb*4 + e
        int tloc = g >> 5;             // 0..15
        int lidx0 = ((tloc >> 2) << 4) + ((hb & 3) << 2);
        int aidx  = ((hb >> 2) << 2) + (tloc & 3);
        float4 sum;
        float* sp = &sum.x;
#pragma unroll
        for (int e = 0; e < 4; ++e) {
            int lidx = lidx0 + e;
            sp[e] = (red[0][lidx][aidx] + red[1][lidx][aidx])
                  + (red[2][lidx][aidx] + red[3][lidx][aidx]);
        }
        size_t gi = (size_t)(ttile * 16 + tloc) * DINNER + hb * 4;
        float4 vres = *(const float4*)(vslice + gi);
        float4 o;
        o.x = fmaf(STD_F, sum.x, vres.x);
        o.y = fmaf(STD_F, sum.y, vres.y);
        o.z = fmaf(STD_F, sum.z, vres.z);
        o.w = fmaf(STD_F, sum.w, vres.w);
        *(float4*)(obase + gi) = o;
    }
}

extern "C" void kernel_launch(void* const* d_in, const int* in_sizes, int n_in,
                              void* d_out, int out_size, void* d_ws, size_t ws_size,
                              hipStream_t stream) {
    const float* v = (const float*)d_in[0];
    const float* q = (const float*)d_in[1];
    const float* k = (const float*)d_in[2];
    float* out = (float*)d_out;
    (void)d_ws; (void)ws_size;   // workspace deliberately UNUSED (poison-fill tax)

    vand_fused<<<dim3(L_SEQ / 16, 16), 256, 0, stream>>>(v, q, k, out);
}

// Round 4
// 74.866 us; speedup vs baseline: 1.2004x; 1.2004x over previous
//
#include <hip/hip_runtime.h>

#define L_SEQ   512
#define NHEADS_ 8
#define HEADDIM_ 128
#define QKD     16
#define DINNER  1024
#define EPS_F   1e-3f
#define STD_F   0.0078125f   // 1/sqrt(2*512*16) = 1/128

// LDS layout for KS[t_local][l]: addr = t*KS_ROW + (l>>5)*33 + (l&31)
// KS_ROW=529 (529%32=17); phase-A stores and phase-B reads both <=2-way (free).
#define KS_ROW  529

typedef __attribute__((ext_vector_type(8))) short  short8;
typedef __attribute__((ext_vector_type(4))) float  floatx4;
typedef __attribute__((ext_vector_type(2))) float  float2v;

// cos(2*pi*rev): v_cos_f32 takes revolutions; reduce to [0,1) first.
__device__ __forceinline__ float cosrev(float rev) {
    float r = rev - floorf(rev);
    return __builtin_amdgcn_cosf(r);
}

// 2*cos(2*pi*a) for tiny |a| (<= ~0.008 rev): even poly, err ~2e-12.
__device__ __forceinline__ float two_cos_small(float a) {
    float x = a * a;
    return fmaf(fmaf(x, 129.8787876f, -39.4784176f), x, 2.0f);
}

// float -> bf16 bits, round-to-nearest-even (for vtrans)
__device__ __forceinline__ unsigned short f2bf_rne(float x) {
    union { float f; unsigned int u; } v;
    v.f = x;
    unsigned int r = v.u + 0x7fffu + ((v.u >> 16) & 1u);
    return (unsigned short)(r >> 16);
}

// 8 floats -> short8 bf16 via v_cvt_pk_bf16_f32 (RNE, 2 floats/inst).
__device__ __forceinline__ short8 pack_bf16x8(const float* s) {
    union { int i[4]; short8 v; } u;
#pragma unroll
    for (int p = 0; p < 4; ++p)
        asm("v_cvt_pk_bf16_f32 %0, %1, %2"
            : "=v"(u.i[p]) : "v"(s[2 * p]), "v"(s[2 * p + 1]));
    return u.v;
}

// Kernel 1: vt layout [bn][lchunk=l>>3][h][l&7] bf16 -- phase-B B-operand loads
// are 16B/lane contiguous across the 16 lanes of an MFMA column group.
__global__ __launch_bounds__(256) void vtrans_kernel(const float* __restrict__ v,
                                                     unsigned short* __restrict__ vt) {
    const int bid = blockIdx.x;
    const int tid = threadIdx.x;
    const int l0 = (bid & 7) * 64;
    const int h0 = ((bid >> 3) & 1) * 64;
    const int bn = bid >> 4;
    const int b = bn >> 3, n = bn & 7;
    __shared__ float tile[64][65];
    const float* vb = v + ((size_t)b * L_SEQ) * DINNER + n * HEADDIM_;
#pragma unroll
    for (int i = 0; i < 16; ++i) {
        int f = i * 256 + tid;
        int hh = f & 63, ll = f >> 6;
        tile[hh][ll] = vb[(size_t)(l0 + ll) * DINNER + (h0 + hh)];
    }
    __syncthreads();
    unsigned short* vdst = vt + (size_t)bn * (64 * 128 * 8);
#pragma unroll
    for (int i = 0; i < 2; ++i) {
        int f = i * 256 + tid;       // 512 groups of 8 shorts
        int hh = f & 63;             // h within tile (innermost -> coalesced stores)
        int lc = f >> 6;             // 0..7 l-chunk within tile
        short8 pk;
#pragma unroll
        for (int j = 0; j < 8; ++j)
            pk[j] = (short)f2bf_rne(tile[hh][lc * 8 + j]);
        *(short8*)(vdst + ((size_t)((l0 >> 3) + lc) * 128 + (h0 + hh)) * 8) = pk;
    }
}

// Kernel 2: 8 WAVES (512 threads) per block, each wave owns a 64-wide l-slice.
// Grid (32,16) x 2 blocks/CU -> 16 waves/CU (2x round-3's 8): the kernel was
// measured pure latency-bound (VALUBusy 12%, MfmaUtil 0.8%, HBM 6%), so the
// lever is waves in flight, not instruction count.
// l-permutation per wave: l = w*64 + quad*16 + c*8 + jj (c in {0,1}).
// Split-K reduction is two-step so red[4][64][33] still overlays ksl (33.9 KB).
__global__ __launch_bounds__(512, 4) void vand_fused(const float* __restrict__ v,
                                                     const float* __restrict__ q,
                                                     const float* __restrict__ k,
                                                     const unsigned short* __restrict__ vt,
                                                     float* __restrict__ out) {
    const int tid  = threadIdx.x;
    const int w    = tid >> 6;        // 0..7
    const int lane = tid & 63;
    const int tl   = lane & 15;
    const int quad = lane >> 4;
    const int ttile = blockIdx.x;     // 0..31
    const int bn    = blockIdx.y;     // 0..15
    const int b = bn >> 3, n = bn & 7;
    const float t0f = (float)(ttile * 16);

    __shared__ float smem[16 * KS_ROW];   // 33.9 KB: ksl (A/B), red (epilogue)
    float* ksl = smem;

    // ---- Phase A: KS[t][l], wave w covers l in [w*64, w*64+64) (1 l/lane) ----
    // Same-wave write/read in phase B -> no barrier needed between A and B.
    {
        const int l = w * 64 + lane;
        const float* krow = k + ((size_t)(b * L_SEQ + l)) * (NHEADS_ * QKD) + n * QKD;
        float kk[16];
#pragma unroll
        for (int d4 = 0; d4 < 4; ++d4) {
            float4 t4 = *(const float4*)(krow + 4 * d4);
            kk[d4 * 4 + 0] = t4.x; kk[d4 * 4 + 1] = t4.y;
            kk[d4 * 4 + 2] = t4.z; kk[d4 * 4 + 3] = t4.w;
        }
        float2v M2[8], C1[8], C0[8];
#pragma unroll
        for (int i = 0; i < 8; ++i) {
            float a0 = EPS_F * kk[2 * i], a1 = EPS_F * kk[2 * i + 1];
            M2[i].x = two_cos_small(a0);         M2[i].y = two_cos_small(a1);
            C1[i].x = cosrev(a0 * t0f);          C1[i].y = cosrev(a1 * t0f);
            C0[i].x = cosrev(a0 * (t0f - 1.f));  C0[i].y = cosrev(a1 * (t0f - 1.f));
        }
        const int base = (l >> 5) * 33 + (l & 31);
#pragma unroll
        for (int m = 0; m < 16; ++m) {
            float2v s = ((C1[0] + C1[1]) + (C1[2] + C1[3]))
                      + ((C1[4] + C1[5]) + (C1[6] + C1[7]));
            ksl[m * KS_ROW + base] = s.x + s.y;
#pragma unroll
            for (int i = 0; i < 8; ++i) {
                float2v nx = M2[i] * C1[i] - C0[i];
                C0[i] = C1[i];
                C1[i] = nx;
            }
        }
    }

    // ---- Phase B: q-part recurrence + subtract KS + MFMA ----
    const int   t   = ttile * 16 + tl;
    const int   l0  = w * 64 + quad * 16;
    const float l0f = (float)l0;

    const float* qrow = q + ((size_t)(b * L_SEQ + t)) * (NHEADS_ * QKD) + n * QKD;
    float2v M2[8], C1[8], C0[8];
#pragma unroll
    for (int d4 = 0; d4 < 4; ++d4) {
        float4 qq = *(const float4*)(qrow + 4 * d4);
        float aa[4] = {EPS_F * qq.x, EPS_F * qq.y, EPS_F * qq.z, EPS_F * qq.w};
#pragma unroll
        for (int e = 0; e < 2; ++e) {
            int i = d4 * 2 + e;
            float a0 = aa[2 * e], a1 = aa[2 * e + 1];
            M2[i].x = two_cos_small(a0);         M2[i].y = two_cos_small(a1);
            C1[i].x = cosrev(a0 * l0f);          C1[i].y = cosrev(a1 * l0f);
            C0[i].x = cosrev(a0 * (l0f - 1.f));  C0[i].y = cosrev(a1 * (l0f - 1.f));
        }
    }

    const unsigned short* vrow = vt + (size_t)bn * (64 * 128 * 8);
    const int klds = tl * KS_ROW + (w * 2 + (quad >> 1)) * 33 + (quad & 1) * 16;

    floatx4 acc[8] = {};

#pragma unroll
    for (int c = 0; c < 2; ++c) {
        // preload B-fragments first: 8 independent 16B global loads overlap
        // with the recurrence VALU below.
        short8 bfr[8];
        const int lcb = (w * 8 + quad * 2 + c) * 128;
#pragma unroll
        for (int ht = 0; ht < 8; ++ht)
            bfr[ht] = *(const short8*)(vrow + (size_t)(lcb + ht * 16 + tl) * 8);

        float kv[8];
#pragma unroll
        for (int jj = 0; jj < 8; ++jj) kv[jj] = ksl[klds + c * 8 + jj];
        float ss[8];
#pragma unroll
        for (int jj = 0; jj < 8; ++jj) {
            float2v sv = ((C1[0] + C1[1]) + (C1[2] + C1[3]))
                       + ((C1[4] + C1[5]) + (C1[6] + C1[7]));
            ss[jj] = (sv.x + sv.y) - kv[jj];
#pragma unroll
            for (int i = 0; i < 8; ++i) {
                float2v nx = M2[i] * C1[i] - C0[i];
                C0[i] = C1[i];
                C1[i] = nx;
            }
        }
        const short8 af = pack_bf16x8(ss);
#pragma unroll
        for (int ht = 0; ht < 8; ++ht)
            acc[ht] = __builtin_amdgcn_mfma_f32_16x16x32_bf16(af, bfr[ht], acc[ht], 0, 0, 0);
    }

    // ---- two-step split-K reduction (8 waves -> 4 slots) + epilogue ----
    __syncthreads();   // all waves done reading ksl before overlay clobbers it
    float (*red)[64][33] = (float (*)[64][33])smem;   // 4*64*33 = 8448 <= 16*529
    if (w >= 4) {
#pragma unroll
        for (int ht = 0; ht < 8; ++ht)
#pragma unroll
            for (int r = 0; r < 4; ++r)
                red[w - 4][lane][ht * 4 + r] = acc[ht][r];
    }
    __syncthreads();
    if (w < 4) {
#pragma unroll
        for (int ht = 0; ht < 8; ++ht)
#pragma unroll
            for (int r = 0; r < 4; ++r)
                red[w][lane][ht * 4 + r] += acc[ht][r];
    }
    __syncthreads();

    const float* vbase = v   + ((size_t)b * L_SEQ) * DINNER + n * HEADDIM_;
    float*       obase = out + ((size_t)b * L_SEQ) * DINNER + n * HEADDIM_;
    {
        int g    = tid;                // 512 float4 groups (16 t x 32 h-quads)
        int hb   = g & 31;             // h = hb*4 + e
        int tloc = g >> 5;             // 0..15
        int lidx0 = ((tloc >> 2) << 4) + ((hb & 3) << 2);
        int aidx  = ((hb >> 2) << 2) + (tloc & 3);
        float4 sum;
        float* sp = &sum.x;
#pragma unroll
        for (int e = 0; e < 4; ++e) {
            int lidx = lidx0 + e;
            sp[e] = (red[0][lidx][aidx] + red[1][lidx][aidx])
                  + (red[2][lidx][aidx] + red[3][lidx][aidx]);
        }
        size_t gi = (size_t)(ttile * 16 + tloc) * DINNER + hb * 4;
        float4 vres = *(const float4*)(vbase + gi);
        float4 o;
        o.x = fmaf(STD_F, sum.x, vres.x);
        o.y = fmaf(STD_F, sum.y, vres.y);
        o.z = fmaf(STD_F, sum.z, vres.z);
        o.w = fmaf(STD_F, sum.w, vres.w);
        *(float4*)(obase + gi) = o;
    }
}

extern "C" void kernel_launch(void* const* d_in, const int* in_sizes, int n_in,
                              void* d_out, int out_size, void* d_ws, size_t ws_size,
                              hipStream_t stream) {
    const float* v = (const float*)d_in[0];
    const float* q = (const float*)d_in[1];
    const float* k = (const float*)d_in[2];
    float* out = (float*)d_out;
    unsigned short* vt = (unsigned short*)d_ws;   // 16*64*128*8 bf16 = 2 MiB
    // (workspace poison fill is unconditional -- using d_ws costs nothing extra)

    vtrans_kernel<<<dim3(256), 256, 0, stream>>>(v, vt);
    vand_fused<<<dim3(L_SEQ / 16, 16), 512, 0, stream>>>(v, q, k, vt, out);
}

// Round 5
// 73.796 us; speedup vs baseline: 1.2178x; 1.0145x over previous
//
#include <hip/hip_runtime.h>

#define L_SEQ   512
#define NHEADS_ 8
#define HEADDIM_ 128
#define QKD     16
#define DINNER  1024
#define EPS_F   1e-3f
#define STD_F   0.0078125f   // 1/sqrt(2*512*16) = 1/128

// LDS layout for KS[t_local][l]: addr = t*KS_ROW + (l>>5)*33 + (l&31)
// KS_ROW=529 (529%32=17); phase-A stores and phase-B reads both <=2-way (free).
#define KS_ROW  529

typedef __attribute__((ext_vector_type(8))) short  short8;
typedef __attribute__((ext_vector_type(4))) float  floatx4;
typedef __attribute__((ext_vector_type(2))) float  float2v;

// cos(2*pi*rev): v_cos_f32 takes revolutions; reduce to [0,1) first.
__device__ __forceinline__ float cosrev(float rev) {
    float r = rev - floorf(rev);
    return __builtin_amdgcn_cosf(r);
}

// 2*cos(2*pi*a) for tiny |a| (<= ~0.008 rev): even poly, err ~2e-12.
__device__ __forceinline__ float two_cos_small(float a) {
    float x = a * a;
    return fmaf(fmaf(x, 129.8787876f, -39.4784176f), x, 2.0f);
}

// float -> bf16 bits, round-to-nearest-even (for vtrans)
__device__ __forceinline__ unsigned short f2bf_rne(float x) {
    union { float f; unsigned int u; } v;
    v.f = x;
    unsigned int r = v.u + 0x7fffu + ((v.u >> 16) & 1u);
    return (unsigned short)(r >> 16);
}

// 8 floats -> short8 bf16 via v_cvt_pk_bf16_f32 (RNE, 2 floats/inst).
__device__ __forceinline__ short8 pack_bf16x8(const float* s) {
    union { int i[4]; short8 v; } u;
#pragma unroll
    for (int p = 0; p < 4; ++p)
        asm("v_cvt_pk_bf16_f32 %0, %1, %2"
            : "=v"(u.i[p]) : "v"(s[2 * p]), "v"(s[2 * p + 1]));
    return u.v;
}

// Kernel 1: vt layout [bn][lchunk=l>>3][h][l&7] bf16.
// v is COLD every iteration (the 256 MiB poison fill sweeps L2/L3), so this is
// the one genuinely HBM-latency-critical stream: load as batched float4
// (4x bytes-in-flight per wave vs the old scalar loads), all 4 issued before
// any LDS write so vmcnt batching can't be broken by interleaved ds ops.
__global__ __launch_bounds__(256) void vtrans_kernel(const float* __restrict__ v,
                                                     unsigned short* __restrict__ vt) {
    const int bid = blockIdx.x;
    const int tid = threadIdx.x;
    const int l0 = (bid & 7) * 64;
    const int h0 = ((bid >> 3) & 1) * 64;
    const int bn = bid >> 4;
    const int b = bn >> 3, n = bn & 7;
    __shared__ float tile[64][65];
    const float* vb = v + ((size_t)b * L_SEQ) * DINNER + n * HEADDIM_;
    // load: f = i*256+tid; hq = f&15 (h-quad), ll = f>>4 (l within tile)
    float4 r[4];
#pragma unroll
    for (int i = 0; i < 4; ++i) {
        int f = i * 256 + tid;
        int hq = f & 15, ll = f >> 4;
        r[i] = *(const float4*)(vb + (size_t)(l0 + ll) * DINNER + (h0 + hq * 4));
    }
#pragma unroll
    for (int i = 0; i < 4; ++i) {
        int f = i * 256 + tid;
        int hq = f & 15, ll = f >> 4;
        tile[hq * 4 + 0][ll] = r[i].x;
        tile[hq * 4 + 1][ll] = r[i].y;
        tile[hq * 4 + 2][ll] = r[i].z;
        tile[hq * 4 + 3][ll] = r[i].w;
    }
    __syncthreads();
    unsigned short* vdst = vt + (size_t)bn * (64 * 128 * 8);
#pragma unroll
    for (int i = 0; i < 2; ++i) {
        int f = i * 256 + tid;       // 512 groups of 8 shorts
        int hh = f & 63;             // h within tile (innermost -> coalesced stores)
        int lc = f >> 6;             // 0..7 l-chunk within tile
        short8 pk;
#pragma unroll
        for (int j = 0; j < 8; ++j)
            pk[j] = (short)f2bf_rne(tile[hh][lc * 8 + j]);
        *(short8*)(vdst + ((size_t)((l0 >> 3) + lc) * 128 + (h0 + hh)) * 8) = pk;
    }
}

// Kernel 2: 4 waves, wave w owns l in [w*128, w*128+128).
// ILP-first restructure: every load whose address is known at kernel entry
// (both k-row reps, q-row, epilogue residual) is ISSUED AT THE TOP; B-fragments
// are software-pipelined one c-step ahead (c=0's issued before the q-init).
// Latency-bound evidence: R3 counters (VALUBusy 12%, MfmaUtil 0.8%, HBM 6%)
// and R2->R4 occupancy doubling changing nothing.
__global__ __launch_bounds__(256, 2) void vand_fused(const float* __restrict__ v,
                                                     const float* __restrict__ q,
                                                     const float* __restrict__ k,
                                                     const unsigned short* __restrict__ vt,
                                                     float* __restrict__ out) {
    const int tid  = threadIdx.x;
    const int w    = tid >> 6;
    const int lane = tid & 63;
    const int tl   = lane & 15;
    const int quad = lane >> 4;
    const int ttile = blockIdx.x;     // 0..31
    const int bn    = blockIdx.y;     // 0..15
    const int b = bn >> 3, n = bn & 7;
    const float t0f = (float)(ttile * 16);

    __shared__ float smem[16 * KS_ROW];   // 33.9 KB: ksl (A/B), red (epilogue)
    float* ksl = smem;

    // ================= top-of-kernel prefetch (addresses all entry-known) ====
    // k rows for BOTH phase-A reps:
    float4 kf[2][4];
#pragma unroll
    for (int rep = 0; rep < 2; ++rep) {
        const int l = w * 128 + rep * 64 + lane;
        const float* krow = k + ((size_t)(b * L_SEQ + l)) * (NHEADS_ * QKD) + n * QKD;
#pragma unroll
        for (int d4 = 0; d4 < 4; ++d4)
            kf[rep][d4] = *(const float4*)(krow + 4 * d4);
    }
    // q row for phase B:
    const int t = ttile * 16 + tl;
    const float* qrow = q + ((size_t)(b * L_SEQ + t)) * (NHEADS_ * QKD) + n * QKD;
    float4 qf[4];
#pragma unroll
    for (int d4 = 0; d4 < 4; ++d4)
        qf[d4] = *(const float4*)(qrow + 4 * d4);
    // epilogue residual (2 float4 per thread):
    const float* vbase = v + ((size_t)b * L_SEQ) * DINNER + n * HEADDIM_;
    float4 vres[2];
    size_t gis[2];
#pragma unroll
    for (int i = 0; i < 2; ++i) {
        int g    = i * 256 + tid;
        int hb   = g & 31;
        int tloc = g >> 5;
        gis[i] = (size_t)(ttile * 16 + tloc) * DINNER + hb * 4;
        vres[i] = *(const float4*)(vbase + gis[i]);
    }

    // ---- Phase A: KS[t][l] for t in tile, l in THIS WAVE's 128-range ----
    // Wave w writes l in [w*128, w*128+128) and reads back only that range in
    // phase B -> same-wave ds ordering suffices, NO __syncthreads needed.
#pragma unroll
    for (int rep = 0; rep < 2; ++rep) {
        const int l = w * 128 + rep * 64 + lane;
        float kk[16];
#pragma unroll
        for (int d4 = 0; d4 < 4; ++d4) {
            kk[d4 * 4 + 0] = kf[rep][d4].x; kk[d4 * 4 + 1] = kf[rep][d4].y;
            kk[d4 * 4 + 2] = kf[rep][d4].z; kk[d4 * 4 + 3] = kf[rep][d4].w;
        }
        float2v M2[8], C1[8], C0[8];
#pragma unroll
        for (int i = 0; i < 8; ++i) {
            float a0 = EPS_F * kk[2 * i], a1 = EPS_F * kk[2 * i + 1];
            M2[i].x = two_cos_small(a0);         M2[i].y = two_cos_small(a1);
            C1[i].x = cosrev(a0 * t0f);          C1[i].y = cosrev(a1 * t0f);
            C0[i].x = cosrev(a0 * (t0f - 1.f));  C0[i].y = cosrev(a1 * (t0f - 1.f));
        }
        const int base = (l >> 5) * 33 + (l & 31);
#pragma unroll
        for (int m = 0; m < 16; ++m) {
            float2v s = ((C1[0] + C1[1]) + (C1[2] + C1[3]))
                      + ((C1[4] + C1[5]) + (C1[6] + C1[7]));
            ksl[m * KS_ROW + base] = s.x + s.y;
#pragma unroll
            for (int i = 0; i < 8; ++i) {
                float2v nx = M2[i] * C1[i] - C0[i];
                C0[i] = C1[i];
                C1[i] = nx;
            }
        }
    }

    // ---- Phase B setup: B-frag pipeline c=0 issued BEFORE the q-init ----
    const unsigned short* vrow = vt + (size_t)bn * (64 * 128 * 8);
    const int vbaseoff = (w * 16 + quad * 4) * 1024 + tl * 8;   // shorts
    short8 bfr[2][8];
#pragma unroll
    for (int ht = 0; ht < 8; ++ht)
        bfr[0][ht] = *(const short8*)((const short*)vrow + vbaseoff + ht * 128);

    const int   l0  = w * 128 + quad * 32;
    const float l0f = (float)l0;
    float2v M2[8], C1[8], C0[8];
#pragma unroll
    for (int d4 = 0; d4 < 4; ++d4) {
        float aa[4] = {EPS_F * qf[d4].x, EPS_F * qf[d4].y,
                       EPS_F * qf[d4].z, EPS_F * qf[d4].w};
#pragma unroll
        for (int e = 0; e < 2; ++e) {
            int i = d4 * 2 + e;
            float a0 = aa[2 * e], a1 = aa[2 * e + 1];
            M2[i].x = two_cos_small(a0);         M2[i].y = two_cos_small(a1);
            C1[i].x = cosrev(a0 * l0f);          C1[i].y = cosrev(a1 * l0f);
            C0[i].x = cosrev(a0 * (l0f - 1.f));  C0[i].y = cosrev(a1 * (l0f - 1.f));
        }
    }

    const int klds = tl * KS_ROW + (4 * w + quad) * 33;
    floatx4 acc[8] = {};

#pragma unroll
    for (int c = 0; c < 4; ++c) {
        // issue NEXT c's B-fragments before this c's recurrence (1-deep pipe)
        if (c < 3) {
#pragma unroll
            for (int ht = 0; ht < 8; ++ht)
                bfr[(c + 1) & 1][ht] = *(const short8*)((const short*)vrow +
                                          vbaseoff + (c + 1) * 1024 + ht * 128);
        }
        float kv[8];
#pragma unroll
        for (int jj = 0; jj < 8; ++jj) kv[jj] = ksl[klds + c * 8 + jj];
        float ss[8];
#pragma unroll
        for (int jj = 0; jj < 8; ++jj) {
            float2v sv = ((C1[0] + C1[1]) + (C1[2] + C1[3]))
                       + ((C1[4] + C1[5]) + (C1[6] + C1[7]));
            ss[jj] = (sv.x + sv.y) - kv[jj];
#pragma unroll
            for (int i = 0; i < 8; ++i) {
                float2v nx = M2[i] * C1[i] - C0[i];
                C0[i] = C1[i];
                C1[i] = nx;
            }
        }
        const short8 af = pack_bf16x8(ss);
#pragma unroll
        for (int ht = 0; ht < 8; ++ht)
            acc[ht] = __builtin_amdgcn_mfma_f32_16x16x32_bf16(af, bfr[c & 1][ht],
                                                              acc[ht], 0, 0, 0);
    }

    // ---- split-K reduction + epilogue (red overlays ksl; barrier both sides) ----
    __syncthreads();   // all waves done reading ksl before it is clobbered
    float (*red)[64][33] = (float (*)[64][33])smem;   // 4*64*33 = 8448 <= 16*529
#pragma unroll
    for (int ht = 0; ht < 8; ++ht)
#pragma unroll
        for (int r = 0; r < 4; ++r)
            red[w][lane][ht * 4 + r] = acc[ht][r];
    __syncthreads();

    float* obase = out + ((size_t)b * L_SEQ) * DINNER + n * HEADDIM_;
#pragma unroll
    for (int i = 0; i < 2; ++i) {
        int g    = i * 256 + tid;      // 512 float4 groups (16 t x 32 h-quads)
        int hb   = g & 31;             // h = hb*4 + e
        int tloc = g >> 5;             // 0..15
        int lidx0 = ((tloc >> 2) << 4) + ((hb & 3) << 2);
        int aidx  = ((hb >> 2) << 2) + (tloc & 3);
        float4 sum;
        float* sp = &sum.x;
#pragma unroll
        for (int e = 0; e < 4; ++e) {
            int lidx = lidx0 + e;
            sp[e] = (red[0][lidx][aidx] + red[1][lidx][aidx])
                  + (red[2][lidx][aidx] + red[3][lidx][aidx]);
        }
        float4 o;
        o.x = fmaf(STD_F, sum.x, vres[i].x);
        o.y = fmaf(STD_F, sum.y, vres[i].y);
        o.z = fmaf(STD_F, sum.z, vres[i].z);
        o.w = fmaf(STD_F, sum.w, vres[i].w);
        *(float4*)(obase + gis[i]) = o;
    }
}

extern "C" void kernel_launch(void* const* d_in, const int* in_sizes, int n_in,
                              void* d_out, int out_size, void* d_ws, size_t ws_size,
                              hipStream_t stream) {
    const float* v = (const float*)d_in[0];
    const float* q = (const float*)d_in[1];
    const float* k = (const float*)d_in[2];
    float* out = (float*)d_out;
    unsigned short* vt = (unsigned short*)d_ws;   // 16*64*128*8 bf16 = 2 MiB
    // (workspace poison fill is unconditional -- using d_ws costs nothing extra)

    vtrans_kernel<<<dim3(256), 256, 0, stream>>>(v, vt);
    vand_fused<<<dim3(L_SEQ / 16, 16), 256, 0, stream>>>(v, q, k, vt, out);
}